// Round 5
// baseline (420.125 us; speedup 1.0000x reference)
//
#include <hip/hip_runtime.h>
#include <hip/hip_bf16.h>

typedef __attribute__((ext_vector_type(8))) __bf16 bf16x8;
typedef __attribute__((ext_vector_type(8))) unsigned short us8;
typedef __attribute__((ext_vector_type(4))) float f32x4;
typedef long long ll;

#define GLD(gp, lp) __builtin_amdgcn_global_load_lds( \
    (const __attribute__((address_space(1))) void*)(gp), \
    (__attribute__((address_space(3))) void*)(lp), 16, 0, 0)

#define SBAR()   asm volatile("s_barrier" ::: "memory")
#define VMCNT(N) asm volatile("s_waitcnt vmcnt(" #N ")" ::: "memory")

// ---------------------------------------------------------------------------
// 256x256-tile pipelined 8-region GEMM. C[M,N] = A[M,K] * B[N,K]^T, bf16 in.
// 512 thr = 8 waves (2M x 4N). BK=64, LDS dbuf per K-tile, 2 K-tiles/iter.
// Region p: { MFMA_p (regs from p-1) | stage GLD | ds_reads for p+1 } [bar].
// Counted vmcnt(2) at END of r2 / r6 (before the barrier -> cross-wave vis).
// T2 swizzle: pre-swizzled global source granule + XOR'd ds_read address.
// OP 0: proj C=bf16 (+bias)   OP 1: scores C=bf16 exp(v/32, masked; skip tiles)
// OP 2: PV   C=fp32 (K truncated to row0+256 when masked)
// ---------------------------------------------------------------------------
template<int OP>
__global__ __launch_bounds__(512) void gemm8(
    const __bf16* __restrict__ A, const __bf16* __restrict__ B,
    void* __restrict__ Cp, const float* __restrict__ bias,
    const int* __restrict__ maskp,
    int K, int lda, int ldb, int ldc,
    ll batchA, ll batchB, ll batchC, int gx, int gy)
{
    __shared__ __bf16 LA[2][256][64];
    __shared__ __bf16 LB[2][256][64];

    // bijective XCD swizzle over the flattened grid (total % 8 == 0)
    const int nwg  = gx * gy * gridDim.z;
    const int cpx  = nwg >> 3;
    const int flat = blockIdx.x + gx * (blockIdx.y + gy * blockIdx.z);
    const int swz  = (flat & 7) * cpx + (flat >> 3);
    const int bx   = swz % gx;
    const int by   = (swz / gx) % gy;
    const int bz   = swz / (gx * gy);

    const int t    = threadIdx.x;
    const int w    = t >> 6, lane = t & 63;
    const int wrm  = w >> 2, wcn  = w & 3;
    const int fr   = lane & 15, fq = lane >> 4;
    const int row0 = bx * 256;
    const int col0 = by * 256;
    const int msk  = (OP >= 1) ? maskp[0] : 0;

    // scores: fully-masked tile -> zeros, skip compute
    if (OP == 1 && msk && by > bx) {
        __bf16* C = (__bf16*)Cp + (ll)bz * batchC;
        bf16x8 z = {};
        #pragma unroll 4
        for (int pass = 0; pass < 16; ++pass) {
            int r = pass * 16 + (t >> 5);
            *(bf16x8*)&C[(ll)(row0 + r) * ldc + col0 + (t & 31) * 8] = z;
        }
        return;
    }

    int NT = K / 64;
    if (OP == 2 && msk) NT = (row0 + 256) / 64;
    const int NI = NT / 2;

    const __bf16* Ab = A + (ll)bz * batchA;
    const __bf16* Bb = B + (ll)bz * batchB;

    const int srow = lane >> 3;
    const int cg   = (lane & 7) ^ srow;          // pre-swizzled source granule

    auto stageA = [&](int kt, int h, int slot) {
        #pragma unroll
        for (int is = 0; is < 2; ++is)
            GLD(Ab + (ll)(row0 + h*128 + is*64 + w*8 + srow) * lda + kt*64 + cg*8,
                &LA[slot][h*128 + is*64 + w*8][0]);
    };
    auto stageB = [&](int kt, int h, int slot) {
        #pragma unroll
        for (int is = 0; is < 2; ++is)
            GLD(Bb + (ll)(col0 + h*128 + is*64 + w*8 + srow) * ldb + kt*64 + cg*8,
                &LB[slot][h*128 + is*64 + w*8][0]);
    };

    f32x4  acc[8][4] = {};
    bf16x8 aF[2][2][2];   // [set][fi][ks]
    bf16x8 bF[2][4][2];   // [slot][j][ks]

#define RD_A(SET, SLOT, QQ) \
    _Pragma("unroll") for (int fi = 0; fi < 2; ++fi) \
    _Pragma("unroll") for (int ks = 0; ks < 2; ++ks) { \
        const int rrow = wrm*128 + (((QQ)&3)*2+fi)*16 + fr; \
        aF[SET][fi][ks] = *(const bf16x8*)&LA[SLOT][rrow][((ks*4+fq) ^ (rrow & 7)) << 3]; \
    }
#define RD_B(SLOT) \
    _Pragma("unroll") for (int j = 0; j < 4; ++j) \
    _Pragma("unroll") for (int ks = 0; ks < 2; ++ks) { \
        const int rrow = wcn*64 + j*16 + fr; \
        bF[SLOT][j][ks] = *(const bf16x8*)&LB[SLOT][rrow][((ks*4+fq) ^ (rrow & 7)) << 3]; \
    }
#define MM(SET, SLOT, Q) \
    __builtin_amdgcn_s_setprio(1); \
    _Pragma("unroll") for (int fi = 0; fi < 2; ++fi) \
    _Pragma("unroll") for (int j = 0; j < 4; ++j) \
    _Pragma("unroll") for (int ks = 0; ks < 2; ++ks) \
        acc[(Q)*2+fi][j] = __builtin_amdgcn_mfma_f32_16x16x32_bf16( \
            aF[SET][fi][ks], bF[SLOT][j][ks], acc[(Q)*2+fi][j], 0, 0, 0); \
    __builtin_amdgcn_s_setprio(0);

    // prologue: K-tile0 (A+B)->slot0, B(1)->slot1; drain slot0; first reads
    stageA(0, 0, 0); stageA(0, 1, 0);
    stageB(0, 0, 0); stageB(0, 1, 0);
    stageB(1, 0, 1); stageB(1, 1, 1);
    VMCNT(4);
    SBAR();
    RD_B(0); RD_A(0, 0, 0);

#define ITER(NL, k1, k2, k3) \
    /*r0*/ MM(0,0,0); stageA(k1,0,1);                      RD_A(1,0,1); SBAR(); \
    /*r1*/ MM(1,0,1); stageA(k1,1,1);                      RD_A(0,0,2); SBAR(); \
    /*r2*/ MM(0,0,2); if (NL) stageB(k2,0,0);              RD_A(1,0,3); \
           if (NL) { VMCNT(2); } else { VMCNT(0); }        SBAR(); \
    /*r3*/ MM(1,0,3); if (NL) stageB(k2,1,0);              RD_B(1); RD_A(0,1,0); SBAR(); \
    /*r4*/ MM(0,1,0); if (NL) stageA(k2,0,0);              RD_A(1,1,1); SBAR(); \
    /*r5*/ MM(1,1,1); if (NL) stageA(k2,1,0);              RD_A(0,1,2); SBAR(); \
    /*r6*/ MM(0,1,2); if (NL) stageB(k3,0,1);              RD_A(1,1,3); \
           if (NL) { VMCNT(2); }                           SBAR(); \
    /*r7*/ MM(1,1,3); if (NL) stageB(k3,1,1); \
           if (NL) { RD_B(0); RD_A(0,0,0); }               SBAR();

    for (int i = 0; i < NI - 1; ++i) {
        const int k1 = 2*i + 1, k2 = 2*i + 2, k3 = 2*i + 3;
        ITER(1, k1, k2, k3)
    }
    {   // peeled last iteration
        const int k1 = 2*(NI-1) + 1;
        ITER(0, k1, 0, 0)
    }
#undef ITER
#undef MM
#undef RD_A
#undef RD_B

    // epilogue
    const ll coff = (ll)bz * batchC;
    #pragma unroll
    for (int fi = 0; fi < 8; ++fi)
    #pragma unroll
    for (int j = 0; j < 4; ++j)
    #pragma unroll
    for (int r4 = 0; r4 < 4; ++r4) {
        const int row = row0 + wrm*128 + fi*16 + fq*4 + r4;
        const int col = col0 + wcn*64 + j*16 + fr;
        float v = acc[fi][j][r4];
        if (OP == 0) {
            v += bias[col];
            ((__bf16*)Cp)[coff + (ll)row * ldc + col] = (__bf16)v;
        } else if (OP == 1) {
            float e = (msk && col > row) ? 0.f : __expf(v * 0.03125f);
            ((__bf16*)Cp)[coff + (ll)row * ldc + col] = (__bf16)e;
        } else {
            ((float*)Cp)[coff + (ll)row * ldc + col] = v;
        }
    }
}

// ---------------------------------------------------------------------------
__global__ __launch_bounds__(256) void cvt_k(const float* __restrict__ in,
                                             __bf16* __restrict__ out, int n8)
{
    const int i = blockIdx.x * 256 + threadIdx.x;
    if (i >= n8) return;
    const f32x4* p = (const f32x4*)(in + (ll)i * 8);
    f32x4 a = p[0], b = p[1];
    bf16x8 h;
    #pragma unroll
    for (int j = 0; j < 4; ++j) { h[j] = (__bf16)a[j]; h[j + 4] = (__bf16)b[j]; }
    *(bf16x8*)(out + (ll)i * 8) = h;
}

__global__ __launch_bounds__(256) void cvtb_k(const float* __restrict__ q,
                                              const float* __restrict__ k,
                                              const float* __restrict__ v,
                                              float* __restrict__ bb)
{
    const int i = blockIdx.x * 256 + threadIdx.x;
    bb[i] = (i < 1024) ? q[i] : (i < 2048) ? k[i - 1024] : v[i - 2048];
}

// ---------------------------------------------------------------------------
__global__ __launch_bounds__(256) void vt_k(const unsigned short* __restrict__ qkv,
                                            unsigned short* __restrict__ vt)
{
    __shared__ unsigned short tile[64][72];
    const int t  = threadIdx.x;
    const int m0 = blockIdx.x * 64;
    const int k0 = blockIdx.y * 64;
    const int b  = blockIdx.z;

    const unsigned short* V = qkv + (ll)b * 2048 * 3072 + 2048;
    #pragma unroll
    for (int h = 0; h < 2; ++h) {
        int r = (t >> 3) + h * 32;
        int c = (t & 7) * 8;
        us8 v = *(const us8*)&V[(ll)(m0 + r) * 3072 + k0 + c];
        *(us8*)&tile[r][c] = v;
    }
    __syncthreads();
    unsigned short* O = vt + (ll)b * 1024 * 2048;
    #pragma unroll
    for (int h = 0; h < 2; ++h) {
        int k = (t >> 3) + h * 32;
        int m = (t & 7) * 8;
        us8 o;
        #pragma unroll
        for (int j = 0; j < 8; ++j) o[j] = tile[m + j][k];
        *(us8*)&O[(ll)(k0 + k) * 2048 + m0 + m] = o;
    }
}

// ---------------------------------------------------------------------------
__global__ __launch_bounds__(256) void colsum_k(const __bf16* __restrict__ E,
                                                float* __restrict__ part)
{
    const int lc = blockIdx.x, mc = blockIdx.y, b = blockIdx.z;
    const int m  = mc * 256 + threadIdx.x;
    const __bf16* p = E + (ll)b * 2048 * 2048 + (ll)(lc * 256) * 2048 + m;
    float s = 0.f;
    #pragma unroll 4
    for (int l = 0; l < 256; ++l) s += (float)p[(ll)l * 2048];
    part[((ll)lc * 8 + b) * 2048 + m] = s;
}

__global__ __launch_bounds__(256) void norm_k(const __bf16* __restrict__ E,
                                              const float* __restrict__ part,
                                              float* __restrict__ attn,
                                              __bf16* __restrict__ attn_bf)
{
    const int lc = blockIdx.x, mc = blockIdx.y, b = blockIdx.z;
    const int m  = mc * 256 + threadIdx.x;
    float s = 0.f;
    #pragma unroll
    for (int j = 0; j < 8; ++j) s += part[((ll)j * 8 + b) * 2048 + m];
    const float inv = 1.0f / s;
    const __bf16* p = E + (ll)b * 2048 * 2048 + (ll)(lc * 256) * 2048 + m;
    float*  qo = attn    + (ll)b * 2048 * 2048 + (ll)(lc * 256) * 2048 + m;
    __bf16* ro = attn_bf + (ll)b * 2048 * 2048 + (ll)(lc * 256) * 2048 + m;
    #pragma unroll 4
    for (int l = 0; l < 256; ++l) {
        float a = (float)p[(ll)l * 2048] * inv;
        qo[(ll)l * 2048] = a;
        ro[(ll)l * 2048] = (__bf16)a;
    }
}

// ---------------------------------------------------------------------------
extern "C" void kernel_launch(void* const* d_in, const int* in_sizes, int n_in,
                              void* d_out, int out_size, void* d_ws, size_t ws_size,
                              hipStream_t stream)
{
    const float* X   = (const float*)d_in[0];
    const float* Wq  = (const float*)d_in[1];
    const float* bq  = (const float*)d_in[2];
    const float* Wk  = (const float*)d_in[3];
    const float* bk  = (const float*)d_in[4];
    const float* Wv  = (const float*)d_in[5];
    const float* bv  = (const float*)d_in[6];
    const int*   msk = (const int*)d_in[7];

    float* out  = (float*)d_out;
    float* attn = out + (ll)8 * 2048 * 1024;

    __bf16* E  = (__bf16*)d_out;                  // bf16 E in out region (dead until PV)
    __bf16* Xb = (__bf16*)attn;                   // staging in attn region
    __bf16* Wb = Xb + (ll)16384 * 1024;
    float*  bb = (float*)(Wb + (ll)3072 * 1024);

    __bf16* qkv = (__bf16*)d_ws;
    __bf16* vt  = qkv + (ll)16384 * 3072;
    float*  prt = (float*)(vt + (ll)8 * 1024 * 2048);
    __bf16* attn_bf = qkv;

    cvt_k<<<dim3(8192), 256, 0, stream>>>(X, Xb, 16384 * 1024 / 8);
    cvt_k<<<dim3(512),  256, 0, stream>>>(Wq, Wb,               1024 * 1024 / 8);
    cvt_k<<<dim3(512),  256, 0, stream>>>(Wk, Wb + 1024 * 1024, 1024 * 1024 / 8);
    cvt_k<<<dim3(512),  256, 0, stream>>>(Wv, Wb + 2048 * 1024, 1024 * 1024 / 8);
    cvtb_k<<<dim3(12),  256, 0, stream>>>(bq, bk, bv, bb);

    gemm8<0><<<dim3(64, 12, 1), 512, 0, stream>>>(
        Xb, Wb, qkv, bb, msk,
        1024, 1024, 1024, 3072, 0LL, 0LL, 0LL, 64, 12);

    vt_k<<<dim3(32, 16, 8), 256, 0, stream>>>((const unsigned short*)qkv,
                                              (unsigned short*)vt);

    gemm8<1><<<dim3(8, 8, 8), 512, 0, stream>>>(
        qkv, qkv + 1024, E, nullptr, msk,
        1024, 3072, 3072, 2048,
        (ll)2048 * 3072, (ll)2048 * 3072, (ll)2048 * 2048, 8, 8);

    colsum_k<<<dim3(8, 8, 8), 256, 0, stream>>>(E, prt);

    norm_k<<<dim3(8, 8, 8), 256, 0, stream>>>(E, prt, attn, attn_bf);

    gemm8<2><<<dim3(8, 4, 8), 512, 0, stream>>>(
        attn_bf, vt, out, nullptr, msk,
        2048, 2048, 2048, 1024,
        (ll)2048 * 2048, (ll)1024 * 2048, (ll)2048 * 1024, 8, 4);
}

// Round 7
// 416.082 us; speedup vs baseline: 1.0097x; 1.0097x over previous
//
#include <hip/hip_runtime.h>
#include <hip/hip_bf16.h>

typedef __attribute__((ext_vector_type(8))) __bf16 bf16x8;
typedef __attribute__((ext_vector_type(8))) unsigned short us8;
typedef __attribute__((ext_vector_type(4))) float f32x4;
typedef long long ll;

#define GLD(gp, lp) __builtin_amdgcn_global_load_lds( \
    (const __attribute__((address_space(1))) void*)(gp), \
    (__attribute__((address_space(3))) void*)(lp), 16, 0, 0)

#define SBAR()   asm volatile("s_barrier" ::: "memory")
#define VMCNT(N) asm volatile("s_waitcnt vmcnt(" #N ")" ::: "memory")

// ---------------------------------------------------------------------------
// 256x256-tile pipelined 8-region GEMM. C[M,N] = A[M,K] * B[N,K]^T, bf16 in.
// 512 thr = 8 waves (2M x 4N). BK=64, LDS dbuf per K-tile, 2 K-tiles/iter.
// Region p: { MFMA_p (regs from p-1) | stage GLD | ds_reads for p+1 } [bar].
// Counted vmcnt(2) at END of r2 / r6 (before the barrier -> cross-wave vis).
// T2 swizzle: pre-swizzled global source granule + XOR'd ds_read address.
// No XCD swizzle (round-5 lesson: tripled proj FETCH_SIZE).
// No in-place PV (round-6 lesson: out rows alias E rows byte-for-byte and
// by-sibling blocks still read E -> cross-block race; PV reads attn_bf copy).
// OP 0: proj C=bf16 (+bias)   OP 1: scores C=bf16 exp(v/32, masked; skip tiles)
// OP 2: PV   C=fp32 (K truncated to row0+256 when masked)
// ---------------------------------------------------------------------------
template<int OP>
__global__ __launch_bounds__(512) void gemm8(
    const __bf16* __restrict__ A, const __bf16* __restrict__ B,
    void* __restrict__ Cp, const float* __restrict__ bias,
    const int* __restrict__ maskp,
    int K, int lda, int ldb, int ldc,
    ll batchA, ll batchB, ll batchC)
{
    __shared__ __bf16 LA[2][256][64];
    __shared__ __bf16 LB[2][256][64];

    const int bx = blockIdx.x, by = blockIdx.y, bz = blockIdx.z;
    const int t    = threadIdx.x;
    const int w    = t >> 6, lane = t & 63;
    const int wrm  = w >> 2, wcn  = w & 3;
    const int fr   = lane & 15, fq = lane >> 4;
    const int row0 = bx * 256;
    const int col0 = by * 256;
    const int msk  = (OP >= 1) ? maskp[0] : 0;

    // scores: fully-masked tile -> zeros, skip compute
    if (OP == 1 && msk && by > bx) {
        __bf16* C = (__bf16*)Cp + (ll)bz * batchC;
        bf16x8 z = {};
        #pragma unroll 4
        for (int pass = 0; pass < 16; ++pass) {
            int r = pass * 16 + (t >> 5);
            *(bf16x8*)&C[(ll)(row0 + r) * ldc + col0 + (t & 31) * 8] = z;
        }
        return;
    }

    int NT = K / 64;
    if (OP == 2 && msk) NT = (row0 + 256) / 64;
    const int NI = NT / 2;

    const __bf16* Ab = A + (ll)bz * batchA;
    const __bf16* Bb = B + (ll)bz * batchB;

    const int srow = lane >> 3;
    const int cg   = (lane & 7) ^ srow;          // pre-swizzled source granule

    auto stageA = [&](int kt, int h, int slot) {
        #pragma unroll
        for (int is = 0; is < 2; ++is)
            GLD(Ab + (ll)(row0 + h*128 + is*64 + w*8 + srow) * lda + kt*64 + cg*8,
                &LA[slot][h*128 + is*64 + w*8][0]);
    };
    auto stageB = [&](int kt, int h, int slot) {
        #pragma unroll
        for (int is = 0; is < 2; ++is)
            GLD(Bb + (ll)(col0 + h*128 + is*64 + w*8 + srow) * ldb + kt*64 + cg*8,
                &LB[slot][h*128 + is*64 + w*8][0]);
    };

    f32x4  acc[8][4] = {};
    bf16x8 aF[2][2][2];   // [set][fi][ks]
    bf16x8 bF[2][4][2];   // [slot][j][ks]

#define RD_A(SET, SLOT, QQ) \
    _Pragma("unroll") for (int fi = 0; fi < 2; ++fi) \
    _Pragma("unroll") for (int ks = 0; ks < 2; ++ks) { \
        const int rrow = wrm*128 + (((QQ)&3)*2+fi)*16 + fr; \
        aF[SET][fi][ks] = *(const bf16x8*)&LA[SLOT][rrow][((ks*4+fq) ^ (rrow & 7)) << 3]; \
    }
#define RD_B(SLOT) \
    _Pragma("unroll") for (int j = 0; j < 4; ++j) \
    _Pragma("unroll") for (int ks = 0; ks < 2; ++ks) { \
        const int rrow = wcn*64 + j*16 + fr; \
        bF[SLOT][j][ks] = *(const bf16x8*)&LB[SLOT][rrow][((ks*4+fq) ^ (rrow & 7)) << 3]; \
    }
#define MM(SET, SLOT, Q) \
    __builtin_amdgcn_s_setprio(1); \
    _Pragma("unroll") for (int fi = 0; fi < 2; ++fi) \
    _Pragma("unroll") for (int j = 0; j < 4; ++j) \
    _Pragma("unroll") for (int ks = 0; ks < 2; ++ks) \
        acc[(Q)*2+fi][j] = __builtin_amdgcn_mfma_f32_16x16x32_bf16( \
            aF[SET][fi][ks], bF[SLOT][j][ks], acc[(Q)*2+fi][j], 0, 0, 0); \
    __builtin_amdgcn_s_setprio(0);

    // prologue: K-tile0 (A+B)->slot0, B(1)->slot1; drain slot0; first reads
    stageA(0, 0, 0); stageA(0, 1, 0);
    stageB(0, 0, 0); stageB(0, 1, 0);
    stageB(1, 0, 1); stageB(1, 1, 1);
    VMCNT(4);
    SBAR();
    RD_B(0); RD_A(0, 0, 0);

#define ITER(NL, k1, k2, k3) \
    /*r0*/ MM(0,0,0); stageA(k1,0,1);                      RD_A(1,0,1); SBAR(); \
    /*r1*/ MM(1,0,1); stageA(k1,1,1);                      RD_A(0,0,2); SBAR(); \
    /*r2*/ MM(0,0,2); if (NL) stageB(k2,0,0);              RD_A(1,0,3); \
           if (NL) { VMCNT(2); } else { VMCNT(0); }        SBAR(); \
    /*r3*/ MM(1,0,3); if (NL) stageB(k2,1,0);              RD_B(1); RD_A(0,1,0); SBAR(); \
    /*r4*/ MM(0,1,0); if (NL) stageA(k2,0,0);              RD_A(1,1,1); SBAR(); \
    /*r5*/ MM(1,1,1); if (NL) stageA(k2,1,0);              RD_A(0,1,2); SBAR(); \
    /*r6*/ MM(0,1,2); if (NL) stageB(k3,0,1);              RD_A(1,1,3); \
           if (NL) { VMCNT(2); }                           SBAR(); \
    /*r7*/ MM(1,1,3); if (NL) stageB(k3,1,1); \
           if (NL) { RD_B(0); RD_A(0,0,0); }               SBAR();

    for (int i = 0; i < NI - 1; ++i) {
        const int k1 = 2*i + 1, k2 = 2*i + 2, k3 = 2*i + 3;
        ITER(1, k1, k2, k3)
    }
    {   // peeled last iteration
        const int k1 = 2*(NI-1) + 1;
        ITER(0, k1, 0, 0)
    }
#undef ITER
#undef MM
#undef RD_A
#undef RD_B

    // epilogue
    const ll coff = (ll)bz * batchC;
    #pragma unroll
    for (int fi = 0; fi < 8; ++fi)
    #pragma unroll
    for (int j = 0; j < 4; ++j)
    #pragma unroll
    for (int r4 = 0; r4 < 4; ++r4) {
        const int row = row0 + wrm*128 + fi*16 + fq*4 + r4;
        const int col = col0 + wcn*64 + j*16 + fr;
        float v = acc[fi][j][r4];
        if (OP == 0) {
            v += bias[col];
            ((__bf16*)Cp)[coff + (ll)row * ldc + col] = (__bf16)v;
        } else if (OP == 1) {
            float e = (msk && col > row) ? 0.f : __expf(v * 0.03125f);
            ((__bf16*)Cp)[coff + (ll)row * ldc + col] = (__bf16)e;
        } else {
            ((float*)Cp)[coff + (ll)row * ldc + col] = v;
        }
    }
}

// ---------------------------------------------------------------------------
__global__ __launch_bounds__(256) void cvt_k(const float* __restrict__ in,
                                             __bf16* __restrict__ out, int n8)
{
    const int i = blockIdx.x * 256 + threadIdx.x;
    if (i >= n8) return;
    const f32x4* p = (const f32x4*)(in + (ll)i * 8);
    f32x4 a = p[0], b = p[1];
    bf16x8 h;
    #pragma unroll
    for (int j = 0; j < 4; ++j) { h[j] = (__bf16)a[j]; h[j + 4] = (__bf16)b[j]; }
    *(bf16x8*)(out + (ll)i * 8) = h;
}

__global__ __launch_bounds__(256) void cvtb_k(const float* __restrict__ q,
                                              const float* __restrict__ k,
                                              const float* __restrict__ v,
                                              float* __restrict__ bb)
{
    const int i = blockIdx.x * 256 + threadIdx.x;
    bb[i] = (i < 1024) ? q[i] : (i < 2048) ? k[i - 1024] : v[i - 2048];
}

// ---------------------------------------------------------------------------
// V transpose: VT[b][k][m] = V[b][m][k]  (bf16, from QKV cols 2048..3071)
// ---------------------------------------------------------------------------
__global__ __launch_bounds__(256) void vt_k(const unsigned short* __restrict__ qkv,
                                            unsigned short* __restrict__ vt)
{
    __shared__ unsigned short tile[64][72];
    const int t  = threadIdx.x;
    const int m0 = blockIdx.x * 64;
    const int k0 = blockIdx.y * 64;
    const int b  = blockIdx.z;

    const unsigned short* V = qkv + (ll)b * 2048 * 3072 + 2048;
    #pragma unroll
    for (int h = 0; h < 2; ++h) {
        int r = (t >> 3) + h * 32;
        int c = (t & 7) * 8;
        us8 v = *(const us8*)&V[(ll)(m0 + r) * 3072 + k0 + c];
        *(us8*)&tile[r][c] = v;
    }
    __syncthreads();
    unsigned short* O = vt + (ll)b * 1024 * 2048;
    #pragma unroll
    for (int h = 0; h < 2; ++h) {
        int k = (t >> 3) + h * 32;
        int m = (t & 7) * 8;
        us8 o;
        #pragma unroll
        for (int j = 0; j < 8; ++j) o[j] = tile[m + j][k];
        *(us8*)&O[(ll)(k0 + k) * 2048 + m0 + m] = o;
    }
}

// ---------------------------------------------------------------------------
// Column softmax over l (per (b,m)), two-phase deterministic. E is bf16.
// ---------------------------------------------------------------------------
__global__ __launch_bounds__(256) void colsum_k(const __bf16* __restrict__ E,
                                                float* __restrict__ part)
{
    const int lc = blockIdx.x, mc = blockIdx.y, b = blockIdx.z;
    const int m  = mc * 256 + threadIdx.x;
    const __bf16* p = E + (ll)b * 2048 * 2048 + (ll)(lc * 256) * 2048 + m;
    float s = 0.f;
    #pragma unroll 4
    for (int l = 0; l < 256; ++l) s += (float)p[(ll)l * 2048];
    part[((ll)lc * 8 + b) * 2048 + m] = s;
}

// attn (fp32, required output) = E * inv; also bf16 copy for PV's A-operand
__global__ __launch_bounds__(256) void norm_k(const __bf16* __restrict__ E,
                                              const float* __restrict__ part,
                                              float* __restrict__ attn,
                                              __bf16* __restrict__ attn_bf)
{
    const int lc = blockIdx.x, mc = blockIdx.y, b = blockIdx.z;
    const int m  = mc * 256 + threadIdx.x;
    float s = 0.f;
    #pragma unroll
    for (int j = 0; j < 8; ++j) s += part[((ll)j * 8 + b) * 2048 + m];
    const float inv = 1.0f / s;
    const __bf16* p = E + (ll)b * 2048 * 2048 + (ll)(lc * 256) * 2048 + m;
    float*  qo = attn    + (ll)b * 2048 * 2048 + (ll)(lc * 256) * 2048 + m;
    __bf16* ro = attn_bf + (ll)b * 2048 * 2048 + (ll)(lc * 256) * 2048 + m;
    #pragma unroll 4
    for (int l = 0; l < 256; ++l) {
        float a = (float)p[(ll)l * 2048] * inv;
        qo[(ll)l * 2048] = a;
        ro[(ll)l * 2048] = (__bf16)a;
    }
}

// ---------------------------------------------------------------------------
extern "C" void kernel_launch(void* const* d_in, const int* in_sizes, int n_in,
                              void* d_out, int out_size, void* d_ws, size_t ws_size,
                              hipStream_t stream)
{
    const float* X   = (const float*)d_in[0];
    const float* Wq  = (const float*)d_in[1];
    const float* bq  = (const float*)d_in[2];
    const float* Wk  = (const float*)d_in[3];
    const float* bk  = (const float*)d_in[4];
    const float* Wv  = (const float*)d_in[5];
    const float* bv  = (const float*)d_in[6];
    const int*   msk = (const int*)d_in[7];

    float* out  = (float*)d_out;                  // (8,2048,1024) fp32
    float* attn = out + (ll)8 * 2048 * 1024;      // (8,2048,2048) fp32

    __bf16* E  = (__bf16*)d_out;                  // bf16 E in out region (dead before PV)
    __bf16* Xb = (__bf16*)attn;                   // staging in attn region (dead by norm)
    __bf16* Wb = Xb + (ll)16384 * 1024;
    float*  bb = (float*)(Wb + (ll)3072 * 1024);

    __bf16* qkv = (__bf16*)d_ws;                  // 16384 x 3072 (96 MiB)
    __bf16* vt  = qkv + (ll)16384 * 3072;         // V^T (32 MiB)
    float*  prt = (float*)(vt + (ll)8 * 1024 * 2048);
    __bf16* attn_bf = qkv;                        // reuse qkv (dead after vt+scores)

    // 0) bf16 conversions
    cvt_k<<<dim3(8192), 256, 0, stream>>>(X, Xb, 16384 * 1024 / 8);
    cvt_k<<<dim3(512),  256, 0, stream>>>(Wq, Wb,               1024 * 1024 / 8);
    cvt_k<<<dim3(512),  256, 0, stream>>>(Wk, Wb + 1024 * 1024, 1024 * 1024 / 8);
    cvt_k<<<dim3(512),  256, 0, stream>>>(Wv, Wb + 2048 * 1024, 1024 * 1024 / 8);
    cvtb_k<<<dim3(12),  256, 0, stream>>>(bq, bk, bv, bb);

    // 1) QKV projection: qkv = Xb @ Wb^T + bb (bf16)
    gemm8<0><<<dim3(64, 12, 1), 512, 0, stream>>>(
        Xb, Wb, qkv, bb, msk,
        1024, 1024, 1024, 3072, 0LL, 0LL, 0LL);

    // 2) V transpose (before qkv is reused by attn_bf)
    vt_k<<<dim3(32, 16, 8), 256, 0, stream>>>((const unsigned short*)qkv,
                                              (unsigned short*)vt);

    // 3) E = exp(Q K^T / 32, masked) bf16 -> out region
    gemm8<1><<<dim3(8, 8, 8), 512, 0, stream>>>(
        qkv, qkv + 1024, E, nullptr, msk,
        1024, 3072, 3072, 2048,
        (ll)2048 * 3072, (ll)2048 * 3072, (ll)2048 * 2048);

    // 4) column sums of E (softmax axis=1 denominators)
    colsum_k<<<dim3(8, 8, 8), 256, 0, stream>>>(E, prt);

    // 5) attn fp32 -> d_out attn region; attn_bf -> qkv region (dead)
    norm_k<<<dim3(8, 8, 8), 256, 0, stream>>>(E, prt, attn, attn_bf);

    // 6) out = attn_bf @ vt^T (overwrites E region; E dead after norm)
    gemm8<2><<<dim3(8, 4, 8), 512, 0, stream>>>(
        attn_bf, vt, out, nullptr, msk,
        2048, 2048, 2048, 1024,
        (ll)2048 * 2048, (ll)1024 * 2048, (ll)2048 * 1024);
}